// Round 1
// baseline (142.347 us; speedup 1.0000x reference)
//
#include <hip/hip_runtime.h>

// QDPPMixer: per batch element (bs = 262144):
//   out[b] = sum_i clip(q_i,-10,10) + log(det(relu(Bn Bn^T + diag(noise*0.1)) + 1e-8) + 1e-8)
// where Bn = row-normalized gathered embeddings (8 x 32).
// Trick: normalized Gram = G[i][j] / (sqrt(G[i][i]) * sqrt(G[j][j])) from the RAW Gram,
// so we never materialize normalized rows.

constexpr int   NA         = 8;
constexpr int   EMBED      = 32;
constexpr float Q_MIN      = -10.0f;
constexpr float Q_MAX      = 10.0f;
constexpr float NOISE_COEF = 0.1f;
constexpr float EPS        = 1e-8f;

__global__ __launch_bounds__(256) void qdpp_kernel(
    const float* __restrict__ agent_qs,
    const int*   __restrict__ states,
    const int*   __restrict__ actions,
    const float* __restrict__ noise,
    const float* __restrict__ W,      // (8000, 32) fp32
    float*       __restrict__ out,
    int bs)
{
    int b = blockIdx.x * blockDim.x + threadIdx.x;
    if (b >= bs) return;
    size_t base = (size_t)b * NA;

    // ---- Q-sum with clip (2x float4, coalesced) ----
    float4 qa = *reinterpret_cast<const float4*>(agent_qs + base);
    float4 qb = *reinterpret_cast<const float4*>(agent_qs + base + 4);
    float qv[8] = {qa.x, qa.y, qa.z, qa.w, qb.x, qb.y, qb.z, qb.w};
    float qsum = 0.0f;
    #pragma unroll
    for (int i = 0; i < 8; i++)
        qsum += fminf(fmaxf(qv[i], Q_MIN), Q_MAX);

    // ---- indices ----
    int4 s0 = *reinterpret_cast<const int4*>(states + base);
    int4 s1 = *reinterpret_cast<const int4*>(states + base + 4);
    int4 a0 = *reinterpret_cast<const int4*>(actions + base);
    int4 a1 = *reinterpret_cast<const int4*>(actions + base + 4);
    int st[8] = {s0.x, s0.y, s0.z, s0.w, s1.x, s1.y, s1.z, s1.w};
    int ac[8] = {a0.x, a0.y, a0.z, a0.w, a1.x, a1.y, a1.z, a1.w};

    const float* rowp[8];
    #pragma unroll
    for (int i = 0; i < 8; i++)
        rowp[i] = W + (size_t)(st[i] * 10 + ac[i] + 1000 * i) * EMBED;

    // ---- raw Gram, upper triangle, accumulated over 8 float4 chunks ----
    float g[8][8];
    #pragma unroll
    for (int i = 0; i < 8; i++)
        #pragma unroll
        for (int j = i; j < 8; j++)
            g[i][j] = 0.0f;

    #pragma unroll
    for (int c = 0; c < 8; c++) {
        float4 v[8];
        #pragma unroll
        for (int i = 0; i < 8; i++)
            v[i] = *reinterpret_cast<const float4*>(rowp[i] + c * 4);
        #pragma unroll
        for (int i = 0; i < 8; i++) {
            #pragma unroll
            for (int j = i; j < 8; j++) {
                g[i][j] = fmaf(v[i].x, v[j].x, g[i][j]);
                g[i][j] = fmaf(v[i].y, v[j].y, g[i][j]);
                g[i][j] = fmaf(v[i].z, v[j].z, g[i][j]);
                g[i][j] = fmaf(v[i].w, v[j].w, g[i][j]);
            }
        }
    }

    // ---- normalization scales from diagonal ----
    float inv[8];
    #pragma unroll
    for (int i = 0; i < 8; i++)
        inv[i] = 1.0f / fmaxf(sqrtf(g[i][i]), 1e-12f);

    // ---- noise ----
    float4 n0 = *reinterpret_cast<const float4*>(noise + base);
    float4 n1 = *reinterpret_cast<const float4*>(noise + base + 4);
    float nz[8] = {n0.x, n0.y, n0.z, n0.w, n1.x, n1.y, n1.z, n1.w};

    // ---- build M = relu(normalized Gram + diag(noise*coef)) + eps ----
    float m[8][8];
    #pragma unroll
    for (int i = 0; i < 8; i++) {
        #pragma unroll
        for (int j = 0; j < 8; j++) {
            float gij = (j >= i) ? g[i][j] : g[j][i];   // static ternary, resolved at compile time
            float val = gij * inv[i] * inv[j];
            if (i == j) val += nz[i] * NOISE_COEF;
            m[i][j] = fmaxf(val, 0.0f) + EPS;
        }
    }

    // ---- determinant via unrolled LU (no pivot: M is diag-dominant in practice,
    //      diag in [1,1.1], off-diag = relu(cos sim of random 32-d unit vectors)) ----
    float det = 1.0f;
    #pragma unroll
    for (int k = 0; k < 8; k++) {
        float p = m[k][k];
        det *= p;
        float ip = 1.0f / p;
        #pragma unroll
        for (int i = k + 1; i < 8; i++) {
            float f = m[i][k] * ip;
            #pragma unroll
            for (int j = k + 1; j < 8; j++)
                m[i][j] = fmaf(-f, m[k][j], m[i][j]);
        }
    }

    out[b] = qsum + logf(det + EPS);
}

extern "C" void kernel_launch(void* const* d_in, const int* in_sizes, int n_in,
                              void* d_out, int out_size, void* d_ws, size_t ws_size,
                              hipStream_t stream) {
    const float* agent_qs = (const float*)d_in[0];
    const int*   states   = (const int*)d_in[1];
    const int*   actions  = (const int*)d_in[2];
    const float* noise    = (const float*)d_in[3];
    const float* W        = (const float*)d_in[4];
    float*       out      = (float*)d_out;

    int bs = in_sizes[0] / NA;   // 4096*64
    const int block = 256;
    int grid = (bs + block - 1) / block;
    qdpp_kernel<<<grid, block, 0, stream>>>(agent_qs, states, actions, noise, W, out, bs);
}

// Round 2
// 141.332 us; speedup vs baseline: 1.0072x; 1.0072x over previous
//
#include <hip/hip_runtime.h>

// QDPPMixer: per batch element (bs = 262144):
//   out[b] = sum_i clip(q_i,-10,10) + log(det(relu(Gn + diag(noise*0.1)) + 1e-8) + 1e-8)
// Gn = normalized Gram built from RAW Gram: Gn[i][j] = G[i][j]/(sqrt(G[i][i])sqrt(G[j][j])).
//
// R2 change vs R1: batch gather loads 16-deep (2 chunks x 8 rows in flight) to
// amortize L2-hit latency; __launch_bounds__(256,4) allows ~128 VGPR; 32-bit
// row offsets off the uniform W base (global_load vaddr = v32 + s64 base).

constexpr int   NA         = 8;
constexpr float Q_MIN      = -10.0f;
constexpr float Q_MAX      = 10.0f;
constexpr float NOISE_COEF = 0.1f;
constexpr float EPS        = 1e-8f;

__global__ __launch_bounds__(256, 4) void qdpp_kernel(
    const float* __restrict__ agent_qs,
    const int*   __restrict__ states,
    const int*   __restrict__ actions,
    const float* __restrict__ noise,
    const float* __restrict__ W,      // (8000, 32) fp32, ~1 MB (L2-resident)
    float*       __restrict__ out,
    int bs)
{
    int b = blockIdx.x * blockDim.x + threadIdx.x;
    if (b >= bs) return;
    size_t base = (size_t)b * NA;

    // ---- indices first: start gathers ASAP ----
    int4 s0 = *reinterpret_cast<const int4*>(states + base);
    int4 s1 = *reinterpret_cast<const int4*>(states + base + 4);
    int4 a0 = *reinterpret_cast<const int4*>(actions + base);
    int4 a1 = *reinterpret_cast<const int4*>(actions + base + 4);

    // 32-bit element offsets from uniform base W (table is 1,024,000 B < 2^31)
    int off[8];
    off[0] = (s0.x * 10 + a0.x         ) * 32;
    off[1] = (s0.y * 10 + a0.y + 1000  ) * 32;
    off[2] = (s0.z * 10 + a0.z + 2000  ) * 32;
    off[3] = (s0.w * 10 + a0.w + 3000  ) * 32;
    off[4] = (s1.x * 10 + a1.x + 4000  ) * 32;
    off[5] = (s1.y * 10 + a1.y + 5000  ) * 32;
    off[6] = (s1.z * 10 + a1.z + 6000  ) * 32;
    off[7] = (s1.w * 10 + a1.w + 7000  ) * 32;

    // ---- Gram accumulators (upper triangle) ----
    float g[8][8];
    #pragma unroll
    for (int i = 0; i < 8; i++)
        #pragma unroll
        for (int j = i; j < 8; j++)
            g[i][j] = 0.0f;

    // ---- 4 batches, each: 16 gather loads in flight (2 chunks x 8 rows) ----
    #pragma unroll
    for (int cc = 0; cc < 4; cc++) {
        float4 va[8], vb[8];
        #pragma unroll
        for (int i = 0; i < 8; i++)
            va[i] = *reinterpret_cast<const float4*>(W + off[i] + cc * 8);
        #pragma unroll
        for (int i = 0; i < 8; i++)
            vb[i] = *reinterpret_cast<const float4*>(W + off[i] + cc * 8 + 4);

        #pragma unroll
        for (int i = 0; i < 8; i++) {
            #pragma unroll
            for (int j = i; j < 8; j++) {
                float acc = g[i][j];
                acc = fmaf(va[i].x, va[j].x, acc);
                acc = fmaf(va[i].y, va[j].y, acc);
                acc = fmaf(va[i].z, va[j].z, acc);
                acc = fmaf(va[i].w, va[j].w, acc);
                acc = fmaf(vb[i].x, vb[j].x, acc);
                acc = fmaf(vb[i].y, vb[j].y, acc);
                acc = fmaf(vb[i].z, vb[j].z, acc);
                acc = fmaf(vb[i].w, vb[j].w, acc);
                g[i][j] = acc;
            }
        }
    }

    // ---- Q-sum with clip (loaded after gathers are in flight) ----
    float4 qa = *reinterpret_cast<const float4*>(agent_qs + base);
    float4 qb = *reinterpret_cast<const float4*>(agent_qs + base + 4);
    float qsum = fminf(fmaxf(qa.x, Q_MIN), Q_MAX) + fminf(fmaxf(qa.y, Q_MIN), Q_MAX)
               + fminf(fmaxf(qa.z, Q_MIN), Q_MAX) + fminf(fmaxf(qa.w, Q_MIN), Q_MAX)
               + fminf(fmaxf(qb.x, Q_MIN), Q_MAX) + fminf(fmaxf(qb.y, Q_MIN), Q_MAX)
               + fminf(fmaxf(qb.z, Q_MIN), Q_MAX) + fminf(fmaxf(qb.w, Q_MIN), Q_MAX);

    // ---- normalization scales from diagonal ----
    float inv[8];
    #pragma unroll
    for (int i = 0; i < 8; i++)
        inv[i] = 1.0f / fmaxf(sqrtf(g[i][i]), 1e-12f);

    // ---- noise ----
    float4 n0 = *reinterpret_cast<const float4*>(noise + base);
    float4 n1 = *reinterpret_cast<const float4*>(noise + base + 4);
    float nz[8] = {n0.x, n0.y, n0.z, n0.w, n1.x, n1.y, n1.z, n1.w};

    // ---- M = relu(normalized Gram + diag(noise*coef)) + eps ----
    float m[8][8];
    #pragma unroll
    for (int i = 0; i < 8; i++) {
        #pragma unroll
        for (int j = 0; j < 8; j++) {
            float gij = (j >= i) ? g[i][j] : g[j][i];   // compile-time select
            float val = gij * inv[i] * inv[j];
            if (i == j) val += nz[i] * NOISE_COEF;
            m[i][j] = fmaxf(val, 0.0f) + EPS;
        }
    }

    // ---- det via unrolled no-pivot LU (M is diag-dominant in practice) ----
    float det = 1.0f;
    #pragma unroll
    for (int k = 0; k < 8; k++) {
        float p = m[k][k];
        det *= p;
        float ip = 1.0f / p;
        #pragma unroll
        for (int i = k + 1; i < 8; i++) {
            float f = m[i][k] * ip;
            #pragma unroll
            for (int j = k + 1; j < 8; j++)
                m[i][j] = fmaf(-f, m[k][j], m[i][j]);
        }
    }

    out[b] = qsum + logf(det + EPS);
}

extern "C" void kernel_launch(void* const* d_in, const int* in_sizes, int n_in,
                              void* d_out, int out_size, void* d_ws, size_t ws_size,
                              hipStream_t stream) {
    const float* agent_qs = (const float*)d_in[0];
    const int*   states   = (const int*)d_in[1];
    const int*   actions  = (const int*)d_in[2];
    const float* noise    = (const float*)d_in[3];
    const float* W        = (const float*)d_in[4];
    float*       out      = (float*)d_out;

    int bs = in_sizes[0] / NA;   // 4096*64 = 262144
    const int block = 256;
    int grid = (bs + block - 1) / block;
    qdpp_kernel<<<grid, block, 0, stream>>>(agent_qs, states, actions, noise, W, out, bs);
}

// Round 3
// 101.530 us; speedup vs baseline: 1.4020x; 1.3920x over previous
//
#include <hip/hip_runtime.h>

// QDPPMixer, R3: cooperative gather — 4 lanes per batch element.
// R1/R2 lesson: per-thread divergent gathers (64 distinct 64B lines per wave
// instr) are concurrency-limited at ~0.37 lane-req/cyc/CU. Fix: lanes within a
// 4-lane group load consecutive float4s of the same embedding row, so each
// gather instr touches 16 lines (one per row) instead of 64, each fetched once.
// Gram = per-lane partial (8 of 32 dims) + butterfly __shfl_xor over the group.
// LU/log redundant in all 4 lanes; lane 0 writes.

constexpr int   NA         = 8;
constexpr float Q_MIN      = -10.0f;
constexpr float Q_MAX      = 10.0f;
constexpr float NOISE_COEF = 0.1f;
constexpr float EPS        = 1e-8f;

__global__ __launch_bounds__(256, 4) void qdpp_kernel(
    const float* __restrict__ agent_qs,
    const int*   __restrict__ states,
    const int*   __restrict__ actions,
    const float* __restrict__ noise,
    const float* __restrict__ W,      // (8000, 32) fp32, rows 128B-aligned
    float*       __restrict__ out,
    int bs)
{
    int tid = blockIdx.x * blockDim.x + threadIdx.x;
    int e = tid >> 2;        // element index (4 lanes per element)
    int l = tid & 3;         // lane within group
    if (e >= bs) return;
    size_t base = (size_t)e * NA;

    // ---- indices: all 4 lanes load the same 32B (TA broadcast-merges) ----
    int4 s0 = *reinterpret_cast<const int4*>(states + base);
    int4 s1 = *reinterpret_cast<const int4*>(states + base + 4);
    int4 a0 = *reinterpret_cast<const int4*>(actions + base);
    int4 a1 = *reinterpret_cast<const int4*>(actions + base + 4);

    int off[8];
    off[0] = (s0.x * 10 + a0.x        ) * 32;
    off[1] = (s0.y * 10 + a0.y + 1000 ) * 32;
    off[2] = (s0.z * 10 + a0.z + 2000 ) * 32;
    off[3] = (s0.w * 10 + a0.w + 3000 ) * 32;
    off[4] = (s1.x * 10 + a1.x + 4000 ) * 32;
    off[5] = (s1.y * 10 + a1.y + 5000 ) * 32;
    off[6] = (s1.z * 10 + a1.z + 6000 ) * 32;
    off[7] = (s1.w * 10 + a1.w + 7000 ) * 32;

    // ---- cooperative gather: lane l takes floats [4l,4l+4) (line 0 of row)
    //      and [16+4l, 16+4l+4) (line 1). Each instr = 16 rows x 1 line. ----
    float4 va[8], vb[8];
    #pragma unroll
    for (int i = 0; i < 8; i++)
        va[i] = *reinterpret_cast<const float4*>(W + off[i] + 4 * l);
    #pragma unroll
    for (int i = 0; i < 8; i++)
        vb[i] = *reinterpret_cast<const float4*>(W + off[i] + 16 + 4 * l);

    // ---- per-lane partial Gram (this lane's 8 of 32 dims), upper triangle ----
    float g[8][8];
    #pragma unroll
    for (int i = 0; i < 8; i++) {
        #pragma unroll
        for (int j = i; j < 8; j++) {
            float acc;
            acc = va[i].x * va[j].x;
            acc = fmaf(va[i].y, va[j].y, acc);
            acc = fmaf(va[i].z, va[j].z, acc);
            acc = fmaf(va[i].w, va[j].w, acc);
            acc = fmaf(vb[i].x, vb[j].x, acc);
            acc = fmaf(vb[i].y, vb[j].y, acc);
            acc = fmaf(vb[i].z, vb[j].z, acc);
            acc = fmaf(vb[i].w, vb[j].w, acc);
            g[i][j] = acc;
        }
    }

    // ---- butterfly reduce across the 4-lane group (quad DPP / swizzle) ----
    #pragma unroll
    for (int i = 0; i < 8; i++) {
        #pragma unroll
        for (int j = i; j < 8; j++) {
            float v = g[i][j];
            v += __shfl_xor(v, 1, 4);
            v += __shfl_xor(v, 2, 4);
            g[i][j] = v;
        }
    }

    // ---- Q-sum with clip (broadcast loads, redundant in all 4 lanes) ----
    float4 qa = *reinterpret_cast<const float4*>(agent_qs + base);
    float4 qb = *reinterpret_cast<const float4*>(agent_qs + base + 4);
    float qsum = fminf(fmaxf(qa.x, Q_MIN), Q_MAX) + fminf(fmaxf(qa.y, Q_MIN), Q_MAX)
               + fminf(fmaxf(qa.z, Q_MIN), Q_MAX) + fminf(fmaxf(qa.w, Q_MIN), Q_MAX)
               + fminf(fmaxf(qb.x, Q_MIN), Q_MAX) + fminf(fmaxf(qb.y, Q_MIN), Q_MAX)
               + fminf(fmaxf(qb.z, Q_MIN), Q_MAX) + fminf(fmaxf(qb.w, Q_MIN), Q_MAX);

    // ---- normalization scales from diagonal ----
    float inv[8];
    #pragma unroll
    for (int i = 0; i < 8; i++)
        inv[i] = 1.0f / fmaxf(sqrtf(g[i][i]), 1e-12f);

    // ---- noise (broadcast) ----
    float4 n0 = *reinterpret_cast<const float4*>(noise + base);
    float4 n1 = *reinterpret_cast<const float4*>(noise + base + 4);
    float nz[8] = {n0.x, n0.y, n0.z, n0.w, n1.x, n1.y, n1.z, n1.w};

    // ---- M = relu(normalized Gram + diag(noise*coef)) + eps ----
    float m[8][8];
    #pragma unroll
    for (int i = 0; i < 8; i++) {
        #pragma unroll
        for (int j = 0; j < 8; j++) {
            float gij = (j >= i) ? g[i][j] : g[j][i];   // compile-time select
            float val = gij * inv[i] * inv[j];
            if (i == j) val += nz[i] * NOISE_COEF;
            m[i][j] = fmaxf(val, 0.0f) + EPS;
        }
    }

    // ---- det via unrolled no-pivot LU (diag-dominant in practice) ----
    float det = 1.0f;
    #pragma unroll
    for (int k = 0; k < 8; k++) {
        float p = m[k][k];
        det *= p;
        float ip = 1.0f / p;
        #pragma unroll
        for (int i = k + 1; i < 8; i++) {
            float f = m[i][k] * ip;
            #pragma unroll
            for (int j = k + 1; j < 8; j++)
                m[i][j] = fmaf(-f, m[k][j], m[i][j]);
        }
    }

    if (l == 0)
        out[e] = qsum + logf(det + EPS);
}

extern "C" void kernel_launch(void* const* d_in, const int* in_sizes, int n_in,
                              void* d_out, int out_size, void* d_ws, size_t ws_size,
                              hipStream_t stream) {
    const float* agent_qs = (const float*)d_in[0];
    const int*   states   = (const int*)d_in[1];
    const int*   actions  = (const int*)d_in[2];
    const float* noise    = (const float*)d_in[3];
    const float* W        = (const float*)d_in[4];
    float*       out      = (float*)d_out;

    int bs = in_sizes[0] / NA;            // 262144
    const int block = 256;
    long long total = (long long)bs * 4;  // 4 lanes per element
    int grid = (int)((total + block - 1) / block);
    qdpp_kernel<<<grid, block, 0, stream>>>(agent_qs, states, actions, noise, W, out, bs);
}